// Round 1
// baseline (1128.805 us; speedup 1.0000x reference)
//
#include <hip/hip_runtime.h>
#include <stdint.h>

// Problem constants (B=4, N=4096, D=512, K=16384, NUM_Q=2)
constexpr int TT = 16384;   // tokens = B*N
constexpr int DD = 512;     // feature dim
constexpr int KK = 16384;   // codebook size
constexpr int TOPK = 8;     // exact-rescore candidates per token

typedef __bf16 bf16x8 __attribute__((ext_vector_type(8)));
typedef __bf16 bf16x4 __attribute__((ext_vector_type(4)));
typedef float f32x4 __attribute__((ext_vector_type(4)));

typedef const __attribute__((address_space(1))) void* gas_ptr;
typedef __attribute__((address_space(3))) void* las_ptr;

// Monotone float -> sortable u32, packed with index. u64 min == (min dist, then min idx),
// matching np.argmin first-occurrence tie-break. (used in exact rescore)
__device__ __forceinline__ unsigned long long pack_di(float d, int idx) {
    uint32_t u = __float_as_uint(d);
    u = (u & 0x80000000u) ? ~u : (u | 0x80000000u);
    return ((unsigned long long)u << 32) | (uint32_t)idx;
}

__device__ __forceinline__ unsigned long long umin64(unsigned long long a,
                                                     unsigned long long b) {
    return a < b ? a : b;
}
__device__ __forceinline__ uint32_t umin32(uint32_t a, uint32_t b) { return a < b ? a : b; }
__device__ __forceinline__ uint32_t umax32(uint32_t a, uint32_t b) { return a > b ? a : b; }

// fp32 -> sortable u32 (monotone)
__device__ __forceinline__ uint32_t sortable(float d) {
    uint32_t u = __float_as_uint(d);
    return u ^ ((uint32_t)((int32_t)u >> 31) | 0x80000000u);
}

// ---------------------------------------------------------------------------
// bf16-MFMA GEMM with fp32-grade accuracy via hi/lo split (3 products):
//   out[m][n] = sum_k Ain[m][k] * W[n][k] + bias[n]
// MODE 0: Ain = A       ; writes out0 (z), out1 (r copy), out2 (bf16 z)
// MODE 1: Ain = A - A2  ; writes out0 only
// 128x128 tile, BK=64, 4 waves 4x1 (32 rows x 128 cols each). N = 512.
// ---------------------------------------------------------------------------
template<int MODE>
__global__ __launch_bounds__(256)
void gemm_mfma(const float* __restrict__ A, const float* __restrict__ A2,
               const float* __restrict__ W, const float* __restrict__ bias,
               float* __restrict__ out0, float* __restrict__ out1,
               __bf16* __restrict__ out2)
{
    __shared__ __bf16 Ah[128 * 64], Al[128 * 64];
    __shared__ __bf16 Bh[128 * 64], Bl[128 * 64];   // 64 KB total
    const int tid = threadIdx.x;
    const int lane = tid & 63;
    const int w = tid >> 6;
    const int row0 = blockIdx.y * 128;
    const int col0 = blockIdx.x * 128;

    f32x4 acc[2][8] = {};

    // staging coords: thread t covers (row = i*16 + t>>4, fp32 cols scol..scol+3)
    const int sr = tid >> 4;            // 0..15
    const int scol = (tid & 15) * 4;    // 0..60
    const int lcol = (((scol >> 3) ^ (sr & 7)) << 3) + (scol & 7);

    int a_off[2], b_off[8];
    #pragma unroll
    for (int mi = 0; mi < 2; ++mi) {
        const int ar = w * 32 + mi * 16 + (lane & 15);
        a_off[mi] = ar * 64 + (((lane >> 4) ^ (ar & 7)) << 3);
    }
    #pragma unroll
    for (int ni = 0; ni < 8; ++ni) {
        const int br = ni * 16 + (lane & 15);
        b_off[ni] = br * 64 + (((lane >> 4) ^ (br & 7)) << 3);
    }

    for (int kb = 0; kb < 512; kb += 64) {
        __syncthreads();
        #pragma unroll
        for (int i = 0; i < 8; ++i) {
            const int r = i * 16 + sr;
            float4 v = *(const float4*)(A + (size_t)(row0 + r) * 512 + kb + scol);
            if (MODE == 1) {
                const float4 u = *(const float4*)(A2 + (size_t)(row0 + r) * 512 + kb + scol);
                v.x -= u.x; v.y -= u.y; v.z -= u.z; v.w -= u.w;
            }
            bf16x4 hv, lv;
            hv[0] = (__bf16)v.x; hv[1] = (__bf16)v.y; hv[2] = (__bf16)v.z; hv[3] = (__bf16)v.w;
            lv[0] = (__bf16)(v.x - (float)hv[0]); lv[1] = (__bf16)(v.y - (float)hv[1]);
            lv[2] = (__bf16)(v.z - (float)hv[2]); lv[3] = (__bf16)(v.w - (float)hv[3]);
            *(bf16x4*)(Ah + r * 64 + lcol) = hv;
            *(bf16x4*)(Al + r * 64 + lcol) = lv;

            const float4 x = *(const float4*)(W + (size_t)(col0 + r) * 512 + kb + scol);
            bf16x4 hw, lw;
            hw[0] = (__bf16)x.x; hw[1] = (__bf16)x.y; hw[2] = (__bf16)x.z; hw[3] = (__bf16)x.w;
            lw[0] = (__bf16)(x.x - (float)hw[0]); lw[1] = (__bf16)(x.y - (float)hw[1]);
            lw[2] = (__bf16)(x.z - (float)hw[2]); lw[3] = (__bf16)(x.w - (float)hw[3]);
            *(bf16x4*)(Bh + r * 64 + lcol) = hw;
            *(bf16x4*)(Bl + r * 64 + lcol) = lw;
        }
        __syncthreads();
        #pragma unroll
        for (int s = 0; s < 2; ++s) {
            const int sx = s * 32;
            bf16x8 ah[2], al[2];
            #pragma unroll
            for (int mi = 0; mi < 2; ++mi) {
                ah[mi] = *(const bf16x8*)(Ah + (a_off[mi] ^ sx));
                al[mi] = *(const bf16x8*)(Al + (a_off[mi] ^ sx));
            }
            #pragma unroll
            for (int ni = 0; ni < 8; ++ni) {
                const bf16x8 bh = *(const bf16x8*)(Bh + (b_off[ni] ^ sx));
                const bf16x8 bl = *(const bf16x8*)(Bl + (b_off[ni] ^ sx));
                #pragma unroll
                for (int mi = 0; mi < 2; ++mi) {
                    acc[mi][ni] = __builtin_amdgcn_mfma_f32_16x16x32_bf16(ah[mi], bh, acc[mi][ni], 0, 0, 0);
                    acc[mi][ni] = __builtin_amdgcn_mfma_f32_16x16x32_bf16(ah[mi], bl, acc[mi][ni], 0, 0, 0);
                    acc[mi][ni] = __builtin_amdgcn_mfma_f32_16x16x32_bf16(al[mi], bh, acc[mi][ni], 0, 0, 0);
                }
            }
        }
    }

    #pragma unroll
    for (int mi = 0; mi < 2; ++mi) {
        #pragma unroll
        for (int reg = 0; reg < 4; ++reg) {
            const int row = row0 + w * 32 + mi * 16 + (lane >> 4) * 4 + reg;
            #pragma unroll
            for (int ni = 0; ni < 8; ++ni) {
                const int col = col0 + ni * 16 + (lane & 15);
                const float o = acc[mi][ni][reg] + bias[col];
                out0[(size_t)row * 512 + col] = o;
                if (MODE == 0) {
                    out1[(size_t)row * 512 + col] = o;
                    out2[(size_t)row * 512 + col] = (__bf16)o;
                }
            }
        }
    }
}

// ---------------------------------------------------------------------------
// Approx distance pass, 256x256 8-phase schedule (T1+T2+T3+T4+T5):
//   d[t][c] ~= csq[c] - 2 * (r16[t] . cb16[c])
// 8 waves (2M x 4N), wave tile 128x64, BK=64, 128 KiB double-buffered LDS.
// Per phase: {ds_read subtile || stage 1 half-tile} -> barrier -> lgkmcnt(0)
// -> setprio(1) 16 MFMA setprio(0) -> barrier.  Counted vmcnt(4) only at
// phases 4/8 (never 0 in steady state) keeps 2 half-tiles in flight across
// barriers.  Stage slots: t+2 A @P3/P4, t+2 B @P5/P6, t+3 A @P7/P8,
// t+3 B @P1/P2 (next iter); buf reads front-loaded 12/8/4/0 so each LDS
// region is register-resident before its overwrite is issued.
// Epilogue: per token-row TOP-2 over each wave's 64 cols (u32 keys, low 6
// bits = local col) -> winners = u32[TT][512], identical layout/tie-break to
// the previous 128x128 version.
// ---------------------------------------------------------------------------
__global__ __launch_bounds__(512, 2)
void dist_approx8(const __bf16* __restrict__ Rh,   // [TT][512]
                  const __bf16* __restrict__ Ch,   // [KK][512]
                  const float* __restrict__ csq,
                  uint32_t* __restrict__ winners)
{
    __shared__ __bf16 As[2][256 * 64];   // 64 KB
    __shared__ __bf16 Bs[2][256 * 64];   // 64 KB

    const int tid  = threadIdx.x;
    const int lane = tid & 63;
    const int w    = tid >> 6;        // 0..7
    const int wm   = w >> 2;          // 0..1 : token half (128 rows)
    const int wn   = w & 3;           // 0..3 : code quarter (64 cols)

    // XCD-aware bijective swizzle: 4096 blocks, 8 XCDs, 512 contiguous per XCD
    const int wg   = (blockIdx.x & 7) * 512 + (blockIdx.x >> 3);
    const int col0 = (wg & 63) << 8;  // code tile base
    const int row0 = (wg >> 6) << 8;  // token tile base

    f32x4 acc[8][4] = {};   // [mi][ni]

    // staging coords: thread covers row (s_r + 64*rr + 128*h), phys chunk tid&7;
    // LDS stays linear for global_load_lds, swizzle applied on the GLOBAL side.
    const int s_r = tid >> 3;                   // 0..63
    const int s_c = (tid & 7) ^ (s_r & 7);      // logical 16B chunk (involution)
    const __bf16* aS = Rh + (size_t)(row0 + s_r) * 512 + s_c * 8;
    const __bf16* bS = Ch + (size_t)(col0 + s_r) * 512 + s_c * 8;
    __bf16* const lA0 = &As[0][0]; __bf16* const lA1 = &As[1][0];
    __bf16* const lB0 = &Bs[0][0]; __bf16* const lB1 = &Bs[1][0];

    // one half-tile (128 rows x 64 cols) = 2 rounds x (512 thr x 16 B)
#define STAGE(SRC, UOFF, DST)                                                      \
    {                                                                              \
        __builtin_amdgcn_global_load_lds((gas_ptr)((SRC) + (UOFF)),                \
                                         (las_ptr)((DST) + w * 8 * 64), 16, 0, 0); \
        __builtin_amdgcn_global_load_lds((gas_ptr)((SRC) + (UOFF) + 64 * 512),     \
                                         (las_ptr)((DST) + (64 + w * 8) * 64), 16, 0, 0); \
    }

    // fragment LDS offsets (elems), swizzle-compensated; kk=1 -> ^32 elems
    int aoff[8], boff[4];
    #pragma unroll
    for (int mi = 0; mi < 8; ++mi) {
        const int r = wm * 128 + mi * 16 + (lane & 15);
        aoff[mi] = r * 64 + (((lane >> 4) ^ (r & 7)) << 3);
    }
    #pragma unroll
    for (int ni = 0; ni < 4; ++ni) {
        const int r = wn * 64 + ni * 16 + (lane & 15);
        boff[ni] = r * 64 + (((lane >> 4) ^ (r & 7)) << 3);
    }

#define BAR __builtin_amdgcn_s_barrier()
#define LGKM0 { asm volatile("s_waitcnt lgkmcnt(0)" ::: "memory"); \
                __builtin_amdgcn_sched_barrier(0); }
#define MFMA_QUAD(AF, A0, BV)                                                  \
    {                                                                          \
        __builtin_amdgcn_s_setprio(1);                                         \
        _Pragma("unroll")                                                      \
        for (int mi = 0; mi < 4; ++mi) {                                       \
            _Pragma("unroll")                                                  \
            for (int ni = 0; ni < 4; ++ni)                                     \
                acc[(A0) + mi][ni] = __builtin_amdgcn_mfma_f32_16x16x32_bf16(  \
                    (AF)[(A0) + mi], (BV)[ni], acc[(A0) + mi][ni], 0, 0, 0);   \
        }                                                                      \
        __builtin_amdgcn_s_setprio(0);                                         \
    }

    // ---- prologue: tile0 (A,B -> buf0), tile1 A (-> buf1); drain to 4 in flight
    STAGE(aS, 0,              lA0);
    STAGE(aS, 128 * 512,      lA0 + 128 * 64);
    STAGE(bS, 0,              lB0);
    STAGE(bS, 128 * 512,      lB0 + 128 * 64);
    STAGE(aS, 64,             lA1);
    STAGE(aS, 128 * 512 + 64, lA1 + 128 * 64);
    asm volatile("s_waitcnt vmcnt(4)" ::: "memory");
    BAR;

    bf16x8 a0[8], a1[8], b0[4], b1[4];

    for (int it = 0; it < 4; ++it) {
        const bool more = it < 3;
        const int kb1 = (2 * it + 1) * 64;
        const int kb2 = (2 * it + 2) * 64;
        const int kb3 = (2 * it + 3) * 64;

        // ---- P1: read buf0 kk0 (12); stage t(odd) B-lo
        #pragma unroll
        for (int mi = 0; mi < 8; ++mi) a0[mi] = *(const bf16x8*)(lA0 + aoff[mi]);
        #pragma unroll
        for (int ni = 0; ni < 4; ++ni) b0[ni] = *(const bf16x8*)(lB0 + boff[ni]);
        STAGE(bS, kb1, lB1);
        BAR; LGKM0;
        MFMA_QUAD(a0, 0, b0);
        BAR;

        // ---- P2: read buf0 A kk1 (8); stage t(odd) B-hi
        #pragma unroll
        for (int mi = 0; mi < 8; ++mi) a1[mi] = *(const bf16x8*)(lA0 + (aoff[mi] ^ 32));
        STAGE(bS, 128 * 512 + kb1, lB1 + 128 * 64);
        BAR; LGKM0;
        MFMA_QUAD(a0, 4, b0);
        BAR;

        // ---- P3: read buf0 B kk1 (4); stage t+2 A-lo (buf0 A fully read by P2)
        #pragma unroll
        for (int ni = 0; ni < 4; ++ni) b1[ni] = *(const bf16x8*)(lB0 + (boff[ni] ^ 32));
        if (more) STAGE(aS, kb2, lA0);
        BAR; LGKM0;
        MFMA_QUAD(a1, 0, b1);
        BAR;

        // ---- P4: stage t+2 A-hi; counted drain for t(odd)
        if (more) STAGE(aS, 128 * 512 + kb2, lA0 + 128 * 64);
        BAR;
        MFMA_QUAD(a1, 4, b1);
        if (more) { asm volatile("s_waitcnt vmcnt(4)" ::: "memory"); }
        else      { asm volatile("s_waitcnt vmcnt(0)" ::: "memory"); }
        BAR;

        // ---- P5: read buf1 kk0 (12); stage t+2 B-lo (buf0 B fully read by P3)
        #pragma unroll
        for (int mi = 0; mi < 8; ++mi) a0[mi] = *(const bf16x8*)(lA1 + aoff[mi]);
        #pragma unroll
        for (int ni = 0; ni < 4; ++ni) b0[ni] = *(const bf16x8*)(lB1 + boff[ni]);
        if (more) STAGE(bS, kb2, lB0);
        BAR; LGKM0;
        MFMA_QUAD(a0, 0, b0);
        BAR;

        // ---- P6: read buf1 A kk1; stage t+2 B-hi
        #pragma unroll
        for (int mi = 0; mi < 8; ++mi) a1[mi] = *(const bf16x8*)(lA1 + (aoff[mi] ^ 32));
        if (more) STAGE(bS, 128 * 512 + kb2, lB0 + 128 * 64);
        BAR; LGKM0;
        MFMA_QUAD(a0, 4, b0);
        BAR;

        // ---- P7: read buf1 B kk1; stage t+3 A-lo
        #pragma unroll
        for (int ni = 0; ni < 4; ++ni) b1[ni] = *(const bf16x8*)(lB1 + (boff[ni] ^ 32));
        if (more) STAGE(aS, kb3, lA1);
        BAR; LGKM0;
        MFMA_QUAD(a1, 0, b1);
        BAR;

        // ---- P8: stage t+3 A-hi; counted drain for t+2
        if (more) STAGE(aS, 128 * 512 + kb3, lA1 + 128 * 64);
        BAR;
        MFMA_QUAD(a1, 4, b1);
        if (more) { asm volatile("s_waitcnt vmcnt(4)" ::: "memory"); }
        BAR;
    }

    // ---- epilogue: per token-row top-2 over this wave's 64 cols, u32 keys.
    // C/D layout (16x16x32): col = lane&15, row = (lane>>4)*4 + reg
    float csv[4];
    #pragma unroll
    for (int ni = 0; ni < 4; ++ni)
        csv[ni] = csq[col0 + wn * 64 + ni * 16 + (lane & 15)];

    const int tile = (col0 >> 6) + wn;   // 0..255 (64-col granule)
    #pragma unroll
    for (int mi = 0; mi < 8; ++mi) {
        #pragma unroll
        for (int reg = 0; reg < 4; ++reg) {
            uint32_t b = 0xFFFFFFFFu, s = 0xFFFFFFFFu;
            #pragma unroll
            for (int ni = 0; ni < 4; ++ni) {
                const float d = fmaf(-2.0f, acc[mi][ni][reg], csv[ni]);
                const uint32_t key = (sortable(d) & 0xFFFFFFC0u)
                                   | (uint32_t)(ni * 16 + (lane & 15));
                const uint32_t nb = umin32(b, key);
                s = umin32(s, umax32(b, key));
                b = nb;
            }
            #pragma unroll
            for (int m = 1; m < 16; m <<= 1) {
                const uint32_t ob = __shfl_xor((int)b, m, 16);
                const uint32_t os = __shfl_xor((int)s, m, 16);
                const uint32_t nb = umin32(b, ob);
                s = umin32(umin32(s, os), umax32(b, ob));
                b = nb;
            }
            if ((lane & 15) == 0) {
                const int row = row0 + wm * 128 + mi * 16 + (lane >> 4) * 4 + reg;
                uint2 v; v.x = b; v.y = s;
                *(uint2*)(winners + (size_t)row * 512 + tile * 2) = v;
            }
        }
    }
#undef STAGE
#undef BAR
#undef LGKM0
#undef MFMA_QUAD
}

// ---------------------------------------------------------------------------
// Per token (one wave): approx top-8 of the 512 stored u32 keys, exact fp32
// rescore, pick true argmin (np tie-break), then fused residual update:
//   r[t] -= cb[best];  r16[t] = bf16(r[t])
// key -> global col: slot j holds tile j>>1 (64-col granule), col low 6 bits.
// ---------------------------------------------------------------------------
__global__ __launch_bounds__(256)
void select_rescore(const uint32_t* __restrict__ winners,
                    const float* __restrict__ CB, const float* __restrict__ csq,
                    float* __restrict__ R, __bf16* __restrict__ R16)
{
    const int w = threadIdx.x >> 6;
    const int lane = threadIdx.x & 63;
    const int token = blockIdx.x * 4 + w;

    const uint32_t* wt = winners + (size_t)token * 512;
    uint4 q0 = *(const uint4*)(wt + lane * 8);
    uint4 q1 = *(const uint4*)(wt + lane * 8 + 4);
    uint32_t k32[8] = {q0.x, q0.y, q0.z, q0.w, q1.x, q1.y, q1.z, q1.w};

    unsigned long long v[8];
    #pragma unroll
    for (int j = 0; j < 8; ++j) {
        const int gcol = ((lane * 8 + j) >> 1) * 64 + (int)(k32[j] & 63u);
        v[j] = ((unsigned long long)k32[j] << 32) | (uint32_t)gcol;
    }

    unsigned long long cand[TOPK];
    #pragma unroll
    for (int t = 0; t < TOPK; ++t) {
        unsigned long long mm = v[0];
        #pragma unroll
        for (int j = 1; j < 8; ++j) mm = umin64(mm, v[j]);
        #pragma unroll
        for (int m = 1; m < 64; m <<= 1)
            mm = umin64(mm, __shfl_xor(mm, m, 64));
        cand[t] = mm;
        #pragma unroll
        for (int j = 0; j < 8; ++j) if (v[j] == mm) v[j] = ~0ull;
    }

    // exact rescore in fp32
    float4 r0 = *(const float4*)(R + (size_t)token * 512 + lane * 8);
    float4 r1 = *(const float4*)(R + (size_t)token * 512 + lane * 8 + 4);

    unsigned long long best = ~0ull;
    #pragma unroll
    for (int t = 0; t < TOPK; ++t) {
        const int col = (int)(cand[t] & 0xFFFFFFFFull);
        const float4 c0 = *(const float4*)(CB + (size_t)col * 512 + lane * 8);
        const float4 c1 = *(const float4*)(CB + (size_t)col * 512 + lane * 8 + 4);
        float dot = r0.x * c0.x;
        dot = fmaf(r0.y, c0.y, dot); dot = fmaf(r0.z, c0.z, dot);
        dot = fmaf(r0.w, c0.w, dot); dot = fmaf(r1.x, c1.x, dot);
        dot = fmaf(r1.y, c1.y, dot); dot = fmaf(r1.z, c1.z, dot);
        dot = fmaf(r1.w, c1.w, dot);
        #pragma unroll
        for (int m = 1; m < 64; m <<= 1) dot += __shfl_xor(dot, m, 64);
        const float d = fmaf(-2.0f, dot, csq[col]);
        best = umin64(best, pack_di(d, col));
    }

    const int bcol = (int)(best & 0xFFFFFFFFull);
    const float4 c0 = *(const float4*)(CB + (size_t)bcol * 512 + lane * 8);
    const float4 c1 = *(const float4*)(CB + (size_t)bcol * 512 + lane * 8 + 4);
    r0.x -= c0.x; r0.y -= c0.y; r0.z -= c0.z; r0.w -= c0.w;
    r1.x -= c1.x; r1.y -= c1.y; r1.z -= c1.z; r1.w -= c1.w;
    *(float4*)(R + (size_t)token * 512 + lane * 8) = r0;
    *(float4*)(R + (size_t)token * 512 + lane * 8 + 4) = r1;
    bf16x8 h;
    h[0] = (__bf16)r0.x; h[1] = (__bf16)r0.y; h[2] = (__bf16)r0.z; h[3] = (__bf16)r0.w;
    h[4] = (__bf16)r1.x; h[5] = (__bf16)r1.y; h[6] = (__bf16)r1.z; h[7] = (__bf16)r1.w;
    *(bf16x8*)(R16 + (size_t)token * 512 + lane * 8) = h;
}

// ---------------------------------------------------------------------------
// Codebook prep (fused): c_sq[k] = ||cb[k]||^2 (fp32) and cb16 = bf16(cb)
// ---------------------------------------------------------------------------
__global__ __launch_bounds__(256)
void prep_cb(const float* __restrict__ CB, float* __restrict__ c_sq,
             __bf16* __restrict__ cb16)
{
    const int wave = threadIdx.x >> 6;
    const int lane = threadIdx.x & 63;
    const int row = blockIdx.x * 4 + wave;
    const float* p = CB + (size_t)row * DD + lane * 8;
    const float4 a = *(const float4*)p;
    const float4 b = *(const float4*)(p + 4);
    bf16x8 h;
    h[0] = (__bf16)a.x; h[1] = (__bf16)a.y; h[2] = (__bf16)a.z; h[3] = (__bf16)a.w;
    h[4] = (__bf16)b.x; h[5] = (__bf16)b.y; h[6] = (__bf16)b.z; h[7] = (__bf16)b.w;
    *(bf16x8*)(cb16 + (size_t)row * DD + lane * 8) = h;
    float s = a.x*a.x + a.y*a.y + a.z*a.z + a.w*a.w
            + b.x*b.x + b.y*b.y + b.z*b.z + b.w*b.w;
    #pragma unroll
    for (int m = 1; m < 64; m <<= 1) s += __shfl_xor(s, m, 64);
    if (lane == 0) c_sq[row] = s;
}

// ---------------------------------------------------------------------------
extern "C" void kernel_launch(void* const* d_in, const int* in_sizes, int n_in,
                              void* d_out, int out_size, void* d_ws, size_t ws_size,
                              hipStream_t stream)
{
    const float* x    = (const float*)d_in[0];
    const float* encw = (const float*)d_in[1];
    const float* encb = (const float*)d_in[2];
    const float* cb   = (const float*)d_in[3];
    const float* decw = (const float*)d_in[4];
    const float* decb = (const float*)d_in[5];
    float* out = (float*)d_out;

    // ws layout: z (32MB) | r (32MB) | cb16 (16MB) | r16 (16MB) | csq  (~96.1MB)
    float* z    = (float*)d_ws;                                  // TT*DD f32
    float* r    = z + (size_t)TT * DD;                           // TT*DD f32
    __bf16* cb16 = (__bf16*)(r + (size_t)TT * DD);               // KK*512 bf16
    __bf16* r16  = cb16 + (size_t)KK * DD;                       // TT*512 bf16
    float* csq  = (float*)(r16 + (size_t)TT * DD);               // KK f32
    // winners table lives in d_out (33.5 MB) — dead before decoder writes out
    uint32_t* winners = (uint32_t*)d_out;                        // TT*512 u32

    const dim3 blk(256);

    // encoder (MFMA hi/lo): z = x @ enc_w^T + enc_b ; r = z ; r16 = bf16(z)
    gemm_mfma<0><<<dim3(DD / 128, TT / 128), blk, 0, stream>>>(
        x, nullptr, encw, encb, z, r, r16);

    // codebook: exact squared norms + bf16 copy (fused, once per call)
    prep_cb<<<dim3(KK / 4), blk, 0, stream>>>(cb, csq, cb16);

    for (int s = 0; s < 2; ++s) {
        dist_approx8<<<dim3((TT / 256) * (KK / 256)), dim3(512), 0, stream>>>(
            r16, cb16, csq, winners);
        select_rescore<<<dim3(TT / 4), blk, 0, stream>>>(winners, cb, csq, r, r16);
    }

    // decoder (MFMA hi/lo): out = (z - r) @ dec_w^T + dec_b
    gemm_mfma<1><<<dim3(DD / 128, TT / 128), blk, 0, stream>>>(
        z, r, decw, decb, out, nullptr, nullptr);
}

// Round 2
// 1046.904 us; speedup vs baseline: 1.0782x; 1.0782x over previous
//
#include <hip/hip_runtime.h>
#include <stdint.h>

// Problem constants (B=4, N=4096, D=512, K=16384, NUM_Q=2)
constexpr int TT = 16384;   // tokens = B*N
constexpr int DD = 512;     // feature dim
constexpr int KK = 16384;   // codebook size
constexpr int TOPK = 8;     // exact-rescore candidates per token

typedef __bf16 bf16x8 __attribute__((ext_vector_type(8)));
typedef __bf16 bf16x4 __attribute__((ext_vector_type(4)));
typedef float f32x4 __attribute__((ext_vector_type(4)));

typedef const __attribute__((address_space(1))) void* gas_ptr;
typedef __attribute__((address_space(3))) void* las_ptr;

// Monotone float -> sortable u32, packed with index. u64 min == (min dist, then min idx),
// matching np.argmin first-occurrence tie-break. (used in exact rescore)
__device__ __forceinline__ unsigned long long pack_di(float d, int idx) {
    uint32_t u = __float_as_uint(d);
    u = (u & 0x80000000u) ? ~u : (u | 0x80000000u);
    return ((unsigned long long)u << 32) | (uint32_t)idx;
}

__device__ __forceinline__ unsigned long long umin64(unsigned long long a,
                                                     unsigned long long b) {
    return a < b ? a : b;
}
__device__ __forceinline__ uint32_t umin32(uint32_t a, uint32_t b) { return a < b ? a : b; }
__device__ __forceinline__ uint32_t umax32(uint32_t a, uint32_t b) { return a > b ? a : b; }

// fp32 -> sortable u32 (monotone)
__device__ __forceinline__ uint32_t sortable(float d) {
    uint32_t u = __float_as_uint(d);
    return u ^ ((uint32_t)((int32_t)u >> 31) | 0x80000000u);
}

// ---------------------------------------------------------------------------
// bf16-MFMA GEMM with fp32-grade accuracy via hi/lo split (3 products):
//   out[m][n] = sum_k Ain[m][k] * W[n][k] + bias[n]
// MODE 0: Ain = A       ; writes out0 (z), out1 (r copy), out2 (bf16 z)
// MODE 1: Ain = A - A2  ; writes out0 only
// 128x128 tile, BK=64, 4 waves 4x1 (32 rows x 128 cols each). N = 512.
// ---------------------------------------------------------------------------
template<int MODE>
__global__ __launch_bounds__(256)
void gemm_mfma(const float* __restrict__ A, const float* __restrict__ A2,
               const float* __restrict__ W, const float* __restrict__ bias,
               float* __restrict__ out0, float* __restrict__ out1,
               __bf16* __restrict__ out2)
{
    __shared__ __bf16 Ah[128 * 64], Al[128 * 64];
    __shared__ __bf16 Bh[128 * 64], Bl[128 * 64];   // 64 KB total
    const int tid = threadIdx.x;
    const int lane = tid & 63;
    const int w = tid >> 6;
    const int row0 = blockIdx.y * 128;
    const int col0 = blockIdx.x * 128;

    f32x4 acc[2][8] = {};

    // staging coords: thread t covers (row = i*16 + t>>4, fp32 cols scol..scol+3)
    const int sr = tid >> 4;            // 0..15
    const int scol = (tid & 15) * 4;    // 0..60
    const int lcol = (((scol >> 3) ^ (sr & 7)) << 3) + (scol & 7);

    int a_off[2], b_off[8];
    #pragma unroll
    for (int mi = 0; mi < 2; ++mi) {
        const int ar = w * 32 + mi * 16 + (lane & 15);
        a_off[mi] = ar * 64 + (((lane >> 4) ^ (ar & 7)) << 3);
    }
    #pragma unroll
    for (int ni = 0; ni < 8; ++ni) {
        const int br = ni * 16 + (lane & 15);
        b_off[ni] = br * 64 + (((lane >> 4) ^ (br & 7)) << 3);
    }

    for (int kb = 0; kb < 512; kb += 64) {
        __syncthreads();
        #pragma unroll
        for (int i = 0; i < 8; ++i) {
            const int r = i * 16 + sr;
            float4 v = *(const float4*)(A + (size_t)(row0 + r) * 512 + kb + scol);
            if (MODE == 1) {
                const float4 u = *(const float4*)(A2 + (size_t)(row0 + r) * 512 + kb + scol);
                v.x -= u.x; v.y -= u.y; v.z -= u.z; v.w -= u.w;
            }
            bf16x4 hv, lv;
            hv[0] = (__bf16)v.x; hv[1] = (__bf16)v.y; hv[2] = (__bf16)v.z; hv[3] = (__bf16)v.w;
            lv[0] = (__bf16)(v.x - (float)hv[0]); lv[1] = (__bf16)(v.y - (float)hv[1]);
            lv[2] = (__bf16)(v.z - (float)hv[2]); lv[3] = (__bf16)(v.w - (float)hv[3]);
            *(bf16x4*)(Ah + r * 64 + lcol) = hv;
            *(bf16x4*)(Al + r * 64 + lcol) = lv;

            const float4 x = *(const float4*)(W + (size_t)(col0 + r) * 512 + kb + scol);
            bf16x4 hw, lw;
            hw[0] = (__bf16)x.x; hw[1] = (__bf16)x.y; hw[2] = (__bf16)x.z; hw[3] = (__bf16)x.w;
            lw[0] = (__bf16)(x.x - (float)hw[0]); lw[1] = (__bf16)(x.y - (float)hw[1]);
            lw[2] = (__bf16)(x.z - (float)hw[2]); lw[3] = (__bf16)(x.w - (float)hw[3]);
            *(bf16x4*)(Bh + r * 64 + lcol) = hw;
            *(bf16x4*)(Bl + r * 64 + lcol) = lw;
        }
        __syncthreads();
        #pragma unroll
        for (int s = 0; s < 2; ++s) {
            const int sx = s * 32;
            bf16x8 ah[2], al[2];
            #pragma unroll
            for (int mi = 0; mi < 2; ++mi) {
                ah[mi] = *(const bf16x8*)(Ah + (a_off[mi] ^ sx));
                al[mi] = *(const bf16x8*)(Al + (a_off[mi] ^ sx));
            }
            #pragma unroll
            for (int ni = 0; ni < 8; ++ni) {
                const bf16x8 bh = *(const bf16x8*)(Bh + (b_off[ni] ^ sx));
                const bf16x8 bl = *(const bf16x8*)(Bl + (b_off[ni] ^ sx));
                #pragma unroll
                for (int mi = 0; mi < 2; ++mi) {
                    acc[mi][ni] = __builtin_amdgcn_mfma_f32_16x16x32_bf16(ah[mi], bh, acc[mi][ni], 0, 0, 0);
                    acc[mi][ni] = __builtin_amdgcn_mfma_f32_16x16x32_bf16(ah[mi], bl, acc[mi][ni], 0, 0, 0);
                    acc[mi][ni] = __builtin_amdgcn_mfma_f32_16x16x32_bf16(al[mi], bh, acc[mi][ni], 0, 0, 0);
                }
            }
        }
    }

    #pragma unroll
    for (int mi = 0; mi < 2; ++mi) {
        #pragma unroll
        for (int reg = 0; reg < 4; ++reg) {
            const int row = row0 + w * 32 + mi * 16 + (lane >> 4) * 4 + reg;
            #pragma unroll
            for (int ni = 0; ni < 8; ++ni) {
                const int col = col0 + ni * 16 + (lane & 15);
                const float o = acc[mi][ni][reg] + bias[col];
                out0[(size_t)row * 512 + col] = o;
                if (MODE == 0) {
                    out1[(size_t)row * 512 + col] = o;
                    out2[(size_t)row * 512 + col] = (__bf16)o;
                }
            }
        }
    }
}

// ---------------------------------------------------------------------------
// Approx distance pass, 256x256 8-phase schedule with TILE-CHAINING:
//   d[t][c] ~= csq[c] - 2 * (r16[t] . cb16[c])
// Grid = 1024 blocks = 64 code-tile-cols x 16 token-groups; each block chains
// CHAIN=4 token tiles (1024 rows) against ONE 256-code tile, so the counted-
// vmcnt pipeline runs 32 K-tiles (16 iterations) without draining -- the
// prologue/pipeline-fill amortizes 4x vs the unchained version, and the
// B-panel is reused 4x back-to-back by the same CU.
// XCD column-stripe swizzle: XCD x owns code-cols [8x, 8x+8): concurrent
// working set per XCD = 8 B-panels (2 MB) + ~4 hot A-tiles < 4 MB L2, so
// stage loads hit L2 and the vmcnt(4) drains stay short.
// Inner machinery (phases, swizzle, frag offsets, epilogue math) is identical
// to the verified R0 kernel. csq loads hoisted to the prologue (col0 is
// block-invariant) so no extra vm ops interleave the counted-vmcnt loop.
// Epilogue fires after every 4th iteration for the completed token tile,
// then acc is re-zeroed; its winner stores perturb vmcnt only conservatively
// (vmcnt retires in issue order).
// ---------------------------------------------------------------------------
constexpr int CHAIN = 4;                      // token tiles chained per block
constexpr size_t TILE_A = 256 * 512;          // elems per token tile

__global__ __launch_bounds__(512, 2)
void dist_approx8(const __bf16* __restrict__ Rh,   // [TT][512]
                  const __bf16* __restrict__ Ch,   // [KK][512]
                  const float* __restrict__ csq,
                  uint32_t* __restrict__ winners)
{
    __shared__ __bf16 As[2][256 * 64];   // 64 KB
    __shared__ __bf16 Bs[2][256 * 64];   // 64 KB

    const int tid  = threadIdx.x;
    const int lane = tid & 63;
    const int w    = tid >> 6;        // 0..7
    const int wm   = w >> 2;          // 0..1 : token half (128 rows)
    const int wn   = w & 3;           // 0..3 : code quarter (64 cols)

    // XCD column-stripe: xcd = b&7 owns code-cols [8*xcd, 8*xcd+8)
    const int b    = blockIdx.x;              // 0..1023
    const int xcd  = b & 7;
    const int i    = b >> 3;                  // 0..127
    const int ct   = xcd * 8 + (i & 7);       // code tile 0..63
    const int tg   = i >> 3;                  // token group 0..15
    const int col0 = ct << 8;                 // code tile base
    const int rowb = tg << 10;                // 1024-token group base

    f32x4 acc[8][4] = {};   // [mi][ni]

    // staging coords: LDS stays linear for global_load_lds, swizzle applied
    // on the GLOBAL side (involution matches the read-side XOR).
    const int s_r = tid >> 3;                   // 0..63
    const int s_c = (tid & 7) ^ (s_r & 7);      // logical 16B chunk
    const __bf16* aS = Rh + (size_t)(rowb + s_r) * 512 + s_c * 8;
    const __bf16* bS = Ch + (size_t)(col0 + s_r) * 512 + s_c * 8;
    __bf16* const lA0 = &As[0][0]; __bf16* const lA1 = &As[1][0];
    __bf16* const lB0 = &Bs[0][0]; __bf16* const lB1 = &Bs[1][0];

    // A-source offset for K-tile q (q = 0..31): tile (q>>3), k-block (q&7)
#define AOFF(q) ((size_t)((q) >> 3) * TILE_A + (size_t)((q) & 7) * 64)

    // one half-tile (128 rows x 64 cols) = 2 rounds x (512 thr x 16 B)
#define STAGE(SRC, UOFF, DST)                                                      \
    {                                                                              \
        __builtin_amdgcn_global_load_lds((gas_ptr)((SRC) + (UOFF)),                \
                                         (las_ptr)((DST) + w * 8 * 64), 16, 0, 0); \
        __builtin_amdgcn_global_load_lds((gas_ptr)((SRC) + (UOFF) + 64 * 512),     \
                                         (las_ptr)((DST) + (64 + w * 8) * 64), 16, 0, 0); \
    }

    // fragment LDS offsets (elems), swizzle-compensated; kk=1 -> ^32 elems
    int aoff[8], boff[4];
    #pragma unroll
    for (int mi = 0; mi < 8; ++mi) {
        const int r = wm * 128 + mi * 16 + (lane & 15);
        aoff[mi] = r * 64 + (((lane >> 4) ^ (r & 7)) << 3);
    }
    #pragma unroll
    for (int ni = 0; ni < 4; ++ni) {
        const int r = wn * 64 + ni * 16 + (lane & 15);
        boff[ni] = r * 64 + (((lane >> 4) ^ (r & 7)) << 3);
    }

#define BAR __builtin_amdgcn_s_barrier()
#define LGKM0 { asm volatile("s_waitcnt lgkmcnt(0)" ::: "memory"); \
                __builtin_amdgcn_sched_barrier(0); }
#define MFMA_QUAD(AF, A0, BV)                                                  \
    {                                                                          \
        __builtin_amdgcn_s_setprio(1);                                         \
        _Pragma("unroll")                                                      \
        for (int mi = 0; mi < 4; ++mi) {                                       \
            _Pragma("unroll")                                                  \
            for (int ni = 0; ni < 4; ++ni)                                     \
                acc[(A0) + mi][ni] = __builtin_amdgcn_mfma_f32_16x16x32_bf16(  \
                    (AF)[(A0) + mi], (BV)[ni], acc[(A0) + mi][ni], 0, 0, 0);   \
        }                                                                      \
        __builtin_amdgcn_s_setprio(0);                                         \
    }

    // ---- csq hoist (col0 is block-invariant); completion covered by the
    // prologue vmcnt(4) below (csv loads are the oldest vm ops).
    float csv[4];
    #pragma unroll
    for (int ni = 0; ni < 4; ++ni)
        csv[ni] = csq[col0 + wn * 64 + ni * 16 + (lane & 15)];
    const int gt = (col0 >> 6) + wn;   // winners 64-col granule index

    // ---- prologue: K-tile0 (A,B -> buf0), K-tile1 A (-> buf1)
    STAGE(aS, AOFF(0),             lA0);
    STAGE(aS, AOFF(0) + 128 * 512, lA0 + 128 * 64);
    STAGE(bS, 0,                   lB0);
    STAGE(bS, 128 * 512,           lB0 + 128 * 64);
    STAGE(aS, AOFF(1),             lA1);
    STAGE(aS, AOFF(1) + 128 * 512, lA1 + 128 * 64);
    asm volatile("s_waitcnt vmcnt(4)" ::: "memory");
    BAR;

    bf16x8 a0[8], a1[8], b0[4], b1[4];

    for (int it = 0; it < 4 * CHAIN; ++it) {
        const bool more = it < 4 * CHAIN - 1;
        const size_t oB1 = (size_t)((2 * it + 1) & 7) * 64;   // B of K-tile 2it+1
        const size_t oA2 = AOFF(2 * it + 2);
        const size_t oB2 = (size_t)((2 * it + 2) & 7) * 64;
        const size_t oA3 = AOFF(2 * it + 3);

        // ---- P1: read buf0 kk0 (12); stage j1 B-lo
        #pragma unroll
        for (int mi = 0; mi < 8; ++mi) a0[mi] = *(const bf16x8*)(lA0 + aoff[mi]);
        #pragma unroll
        for (int ni = 0; ni < 4; ++ni) b0[ni] = *(const bf16x8*)(lB0 + boff[ni]);
        STAGE(bS, oB1, lB1);
        BAR; LGKM0;
        MFMA_QUAD(a0, 0, b0);
        BAR;

        // ---- P2: read buf0 A kk1 (8); stage j1 B-hi
        #pragma unroll
        for (int mi = 0; mi < 8; ++mi) a1[mi] = *(const bf16x8*)(lA0 + (aoff[mi] ^ 32));
        STAGE(bS, 128 * 512 + oB1, lB1 + 128 * 64);
        BAR; LGKM0;
        MFMA_QUAD(a0, 4, b0);
        BAR;

        // ---- P3: read buf0 B kk1 (4); stage j+2 A-lo (buf0 A fully read by P2)
        #pragma unroll
        for (int ni = 0; ni < 4; ++ni) b1[ni] = *(const bf16x8*)(lB0 + (boff[ni] ^ 32));
        if (more) STAGE(aS, oA2, lA0);
        BAR; LGKM0;
        MFMA_QUAD(a1, 0, b1);
        BAR;

        // ---- P4: stage j+2 A-hi; counted drain for j1
        if (more) STAGE(aS, oA2 + 128 * 512, lA0 + 128 * 64);
        BAR;
        MFMA_QUAD(a1, 4, b1);
        if (more) { asm volatile("s_waitcnt vmcnt(4)" ::: "memory"); }
        else      { asm volatile("s_waitcnt vmcnt(0)" ::: "memory"); }
        BAR;

        // ---- P5: read buf1 kk0 (12); stage j+2 B-lo (buf0 B fully read by P3)
        #pragma unroll
        for (int mi = 0; mi < 8; ++mi) a0[mi] = *(const bf16x8*)(lA1 + aoff[mi]);
        #pragma unroll
        for (int ni = 0; ni < 4; ++ni) b0[ni] = *(const bf16x8*)(lB1 + boff[ni]);
        if (more) STAGE(bS, oB2, lB0);
        BAR; LGKM0;
        MFMA_QUAD(a0, 0, b0);
        BAR;

        // ---- P6: read buf1 A kk1; stage j+2 B-hi
        #pragma unroll
        for (int mi = 0; mi < 8; ++mi) a1[mi] = *(const bf16x8*)(lA1 + (aoff[mi] ^ 32));
        if (more) STAGE(bS, 128 * 512 + oB2, lB0 + 128 * 64);
        BAR; LGKM0;
        MFMA_QUAD(a0, 4, b0);
        BAR;

        // ---- P7: read buf1 B kk1; stage j+3 A-lo
        #pragma unroll
        for (int ni = 0; ni < 4; ++ni) b1[ni] = *(const bf16x8*)(lB1 + (boff[ni] ^ 32));
        if (more) STAGE(aS, oA3, lA1);
        BAR; LGKM0;
        MFMA_QUAD(a1, 0, b1);
        BAR;

        // ---- P8: stage j+3 A-hi; counted drain for j+2
        if (more) STAGE(aS, oA3 + 128 * 512, lA1 + 128 * 64);
        BAR;
        MFMA_QUAD(a1, 4, b1);
        if (more) { asm volatile("s_waitcnt vmcnt(4)" ::: "memory"); }
        BAR;

        // ---- per-tile epilogue: token tile T done after every 4th iteration.
        // Top-2 over this wave's 64 cols, u32 keys; C/D layout (16x16x32):
        // col = lane&15, row = (lane>>4)*4 + reg.  Then re-zero acc.
        if ((it & 3) == 3) {
            const int r0t = rowb + (it >> 2) * 256;
            #pragma unroll
            for (int mi = 0; mi < 8; ++mi) {
                #pragma unroll
                for (int reg = 0; reg < 4; ++reg) {
                    uint32_t bk = 0xFFFFFFFFu, sk = 0xFFFFFFFFu;
                    #pragma unroll
                    for (int ni = 0; ni < 4; ++ni) {
                        const float d = fmaf(-2.0f, acc[mi][ni][reg], csv[ni]);
                        const uint32_t key = (sortable(d) & 0xFFFFFFC0u)
                                           | (uint32_t)(ni * 16 + (lane & 15));
                        const uint32_t nb = umin32(bk, key);
                        sk = umin32(sk, umax32(bk, key));
                        bk = nb;
                    }
                    #pragma unroll
                    for (int m = 1; m < 16; m <<= 1) {
                        const uint32_t ob = __shfl_xor((int)bk, m, 16);
                        const uint32_t os = __shfl_xor((int)sk, m, 16);
                        const uint32_t nb = umin32(bk, ob);
                        sk = umin32(umin32(sk, os), umax32(bk, ob));
                        bk = nb;
                    }
                    if ((lane & 15) == 0) {
                        const int row = r0t + wm * 128 + mi * 16 + (lane >> 4) * 4 + reg;
                        uint2 v; v.x = bk; v.y = sk;
                        *(uint2*)(winners + (size_t)row * 512 + gt * 2) = v;
                    }
                }
            }
            #pragma unroll
            for (int mi = 0; mi < 8; ++mi)
                #pragma unroll
                for (int ni = 0; ni < 4; ++ni)
                    acc[mi][ni] = (f32x4){0.f, 0.f, 0.f, 0.f};
        }
    }
#undef STAGE
#undef AOFF
#undef BAR
#undef LGKM0
#undef MFMA_QUAD
}

// ---------------------------------------------------------------------------
// Per token (one wave): approx top-8 of the 512 stored u32 keys, exact fp32
// rescore, pick true argmin (np tie-break), then fused residual update:
//   r[t] -= cb[best];  r16[t] = bf16(r[t])
// key -> global col: slot j holds tile j>>1 (64-col granule), col low 6 bits.
// ---------------------------------------------------------------------------
__global__ __launch_bounds__(256)
void select_rescore(const uint32_t* __restrict__ winners,
                    const float* __restrict__ CB, const float* __restrict__ csq,
                    float* __restrict__ R, __bf16* __restrict__ R16)
{
    const int w = threadIdx.x >> 6;
    const int lane = threadIdx.x & 63;
    const int token = blockIdx.x * 4 + w;

    const uint32_t* wt = winners + (size_t)token * 512;
    uint4 q0 = *(const uint4*)(wt + lane * 8);
    uint4 q1 = *(const uint4*)(wt + lane * 8 + 4);
    uint32_t k32[8] = {q0.x, q0.y, q0.z, q0.w, q1.x, q1.y, q1.z, q1.w};

    unsigned long long v[8];
    #pragma unroll
    for (int j = 0; j < 8; ++j) {
        const int gcol = ((lane * 8 + j) >> 1) * 64 + (int)(k32[j] & 63u);
        v[j] = ((unsigned long long)k32[j] << 32) | (uint32_t)gcol;
    }

    unsigned long long cand[TOPK];
    #pragma unroll
    for (int t = 0; t < TOPK; ++t) {
        unsigned long long mm = v[0];
        #pragma unroll
        for (int j = 1; j < 8; ++j) mm = umin64(mm, v[j]);
        #pragma unroll
        for (int m = 1; m < 64; m <<= 1)
            mm = umin64(mm, __shfl_xor(mm, m, 64));
        cand[t] = mm;
        #pragma unroll
        for (int j = 0; j < 8; ++j) if (v[j] == mm) v[j] = ~0ull;
    }

    // exact rescore in fp32
    float4 r0 = *(const float4*)(R + (size_t)token * 512 + lane * 8);
    float4 r1 = *(const float4*)(R + (size_t)token * 512 + lane * 8 + 4);

    unsigned long long best = ~0ull;
    #pragma unroll
    for (int t = 0; t < TOPK; ++t) {
        const int col = (int)(cand[t] & 0xFFFFFFFFull);
        const float4 c0 = *(const float4*)(CB + (size_t)col * 512 + lane * 8);
        const float4 c1 = *(const float4*)(CB + (size_t)col * 512 + lane * 8 + 4);
        float dot = r0.x * c0.x;
        dot = fmaf(r0.y, c0.y, dot); dot = fmaf(r0.z, c0.z, dot);
        dot = fmaf(r0.w, c0.w, dot); dot = fmaf(r1.x, c1.x, dot);
        dot = fmaf(r1.y, c1.y, dot); dot = fmaf(r1.z, c1.z, dot);
        dot = fmaf(r1.w, c1.w, dot);
        #pragma unroll
        for (int m = 1; m < 64; m <<= 1) dot += __shfl_xor(dot, m, 64);
        const float d = fmaf(-2.0f, dot, csq[col]);
        best = umin64(best, pack_di(d, col));
    }

    const int bcol = (int)(best & 0xFFFFFFFFull);
    const float4 c0 = *(const float4*)(CB + (size_t)bcol * 512 + lane * 8);
    const float4 c1 = *(const float4*)(CB + (size_t)bcol * 512 + lane * 8 + 4);
    r0.x -= c0.x; r0.y -= c0.y; r0.z -= c0.z; r0.w -= c0.w;
    r1.x -= c1.x; r1.y -= c1.y; r1.z -= c1.z; r1.w -= c1.w;
    *(float4*)(R + (size_t)token * 512 + lane * 8) = r0;
    *(float4*)(R + (size_t)token * 512 + lane * 8 + 4) = r1;
    bf16x8 h;
    h[0] = (__bf16)r0.x; h[1] = (__bf16)r0.y; h[2] = (__bf16)r0.z; h[3] = (__bf16)r0.w;
    h[4] = (__bf16)r1.x; h[5] = (__bf16)r1.y; h[6] = (__bf16)r1.z; h[7] = (__bf16)r1.w;
    *(bf16x8*)(R16 + (size_t)token * 512 + lane * 8) = h;
}

// ---------------------------------------------------------------------------
// Codebook prep (fused): c_sq[k] = ||cb[k]||^2 (fp32) and cb16 = bf16(cb)
// ---------------------------------------------------------------------------
__global__ __launch_bounds__(256)
void prep_cb(const float* __restrict__ CB, float* __restrict__ c_sq,
             __bf16* __restrict__ cb16)
{
    const int wave = threadIdx.x >> 6;
    const int lane = threadIdx.x & 63;
    const int row = blockIdx.x * 4 + wave;
    const float* p = CB + (size_t)row * DD + lane * 8;
    const float4 a = *(const float4*)p;
    const float4 b = *(const float4*)(p + 4);
    bf16x8 h;
    h[0] = (__bf16)a.x; h[1] = (__bf16)a.y; h[2] = (__bf16)a.z; h[3] = (__bf16)a.w;
    h[4] = (__bf16)b.x; h[5] = (__bf16)b.y; h[6] = (__bf16)b.z; h[7] = (__bf16)b.w;
    *(bf16x8*)(cb16 + (size_t)row * DD + lane * 8) = h;
    float s = a.x*a.x + a.y*a.y + a.z*a.z + a.w*a.w
            + b.x*b.x + b.y*b.y + b.z*b.z + b.w*b.w;
    #pragma unroll
    for (int m = 1; m < 64; m <<= 1) s += __shfl_xor(s, m, 64);
    if (lane == 0) c_sq[row] = s;
}

// ---------------------------------------------------------------------------
extern "C" void kernel_launch(void* const* d_in, const int* in_sizes, int n_in,
                              void* d_out, int out_size, void* d_ws, size_t ws_size,
                              hipStream_t stream)
{
    const float* x    = (const float*)d_in[0];
    const float* encw = (const float*)d_in[1];
    const float* encb = (const float*)d_in[2];
    const float* cb   = (const float*)d_in[3];
    const float* decw = (const float*)d_in[4];
    const float* decb = (const float*)d_in[5];
    float* out = (float*)d_out;

    // ws layout: z (32MB) | r (32MB) | cb16 (16MB) | r16 (16MB) | csq  (~96.1MB)
    float* z    = (float*)d_ws;                                  // TT*DD f32
    float* r    = z + (size_t)TT * DD;                           // TT*DD f32
    __bf16* cb16 = (__bf16*)(r + (size_t)TT * DD);               // KK*512 bf16
    __bf16* r16  = cb16 + (size_t)KK * DD;                       // TT*512 bf16
    float* csq  = (float*)(r16 + (size_t)TT * DD);               // KK f32
    // winners table lives in d_out (33.5 MB) — dead before decoder writes out
    uint32_t* winners = (uint32_t*)d_out;                        // TT*512 u32

    const dim3 blk(256);

    // encoder (MFMA hi/lo): z = x @ enc_w^T + enc_b ; r = z ; r16 = bf16(z)
    gemm_mfma<0><<<dim3(DD / 128, TT / 128), blk, 0, stream>>>(
        x, nullptr, encw, encb, z, r, r16);

    // codebook: exact squared norms + bf16 copy (fused, once per call)
    prep_cb<<<dim3(KK / 4), blk, 0, stream>>>(cb, csq, cb16);

    for (int s = 0; s < 2; ++s) {
        // 1024 blocks = 64 code-tiles x 16 token-groups (CHAIN=4 tiles each)
        dist_approx8<<<dim3((KK / 256) * (TT / 256 / CHAIN)), dim3(512), 0, stream>>>(
            r16, cb16, csq, winners);
        select_rescore<<<dim3(TT / 4), blk, 0, stream>>>(winners, cb, csq, r, r16);
    }

    // decoder (MFMA hi/lo): out = (z - r) @ dec_w^T + dec_b
    gemm_mfma<1><<<dim3(DD / 128, TT / 128), blk, 0, stream>>>(
        z, r, decw, decb, out, nullptr, nullptr);
}

// Round 3
// 1006.684 us; speedup vs baseline: 1.1213x; 1.0400x over previous
//
#include <hip/hip_runtime.h>
#include <stdint.h>

// Problem constants (B=4, N=4096, D=512, K=16384, NUM_Q=2)
constexpr int TT = 16384;   // tokens = B*N
constexpr int DD = 512;     // feature dim
constexpr int KK = 16384;   // codebook size
constexpr int TOPK = 8;     // exact-rescore candidates per token

typedef __bf16 bf16x8 __attribute__((ext_vector_type(8)));
typedef __bf16 bf16x4 __attribute__((ext_vector_type(4)));
typedef float f32x4 __attribute__((ext_vector_type(4)));

typedef const __attribute__((address_space(1))) void* gas_ptr;
typedef __attribute__((address_space(3))) void* las_ptr;

// Monotone float -> sortable u32, packed with index. u64 min == (min dist, then min idx),
// matching np.argmin first-occurrence tie-break. (used in exact rescore)
__device__ __forceinline__ unsigned long long pack_di(float d, int idx) {
    uint32_t u = __float_as_uint(d);
    u = (u & 0x80000000u) ? ~u : (u | 0x80000000u);
    return ((unsigned long long)u << 32) | (uint32_t)idx;
}

__device__ __forceinline__ unsigned long long umin64(unsigned long long a,
                                                     unsigned long long b) {
    return a < b ? a : b;
}
__device__ __forceinline__ uint32_t umin32(uint32_t a, uint32_t b) { return a < b ? a : b; }
__device__ __forceinline__ uint32_t umax32(uint32_t a, uint32_t b) { return a > b ? a : b; }

// fp32 -> sortable u32 (monotone)
__device__ __forceinline__ uint32_t sortable(float d) {
    uint32_t u = __float_as_uint(d);
    return u ^ ((uint32_t)((int32_t)u >> 31) | 0x80000000u);
}

// ---------------------------------------------------------------------------
// bf16-MFMA GEMM with fp32-grade accuracy via hi/lo split (3 products):
//   out[m][n] = sum_k Ain[m][k] * W[n][k] + bias[n]
// MODE 0: Ain = A       ; writes out0 (z), out1 (r copy), out2 (bf16 z)
// MODE 1: Ain = A - A2  ; writes out0 only
// 128x128 tile, BK=64, 4 waves 4x1 (32 rows x 128 cols each). N = 512.
// ---------------------------------------------------------------------------
template<int MODE>
__global__ __launch_bounds__(256)
void gemm_mfma(const float* __restrict__ A, const float* __restrict__ A2,
               const float* __restrict__ W, const float* __restrict__ bias,
               float* __restrict__ out0, float* __restrict__ out1,
               __bf16* __restrict__ out2)
{
    __shared__ __bf16 Ah[128 * 64], Al[128 * 64];
    __shared__ __bf16 Bh[128 * 64], Bl[128 * 64];   // 64 KB total
    const int tid = threadIdx.x;
    const int lane = tid & 63;
    const int w = tid >> 6;
    const int row0 = blockIdx.y * 128;
    const int col0 = blockIdx.x * 128;

    f32x4 acc[2][8] = {};

    // staging coords: thread t covers (row = i*16 + t>>4, fp32 cols scol..scol+3)
    const int sr = tid >> 4;            // 0..15
    const int scol = (tid & 15) * 4;    // 0..60
    const int lcol = (((scol >> 3) ^ (sr & 7)) << 3) + (scol & 7);

    int a_off[2], b_off[8];
    #pragma unroll
    for (int mi = 0; mi < 2; ++mi) {
        const int ar = w * 32 + mi * 16 + (lane & 15);
        a_off[mi] = ar * 64 + (((lane >> 4) ^ (ar & 7)) << 3);
    }
    #pragma unroll
    for (int ni = 0; ni < 8; ++ni) {
        const int br = ni * 16 + (lane & 15);
        b_off[ni] = br * 64 + (((lane >> 4) ^ (br & 7)) << 3);
    }

    for (int kb = 0; kb < 512; kb += 64) {
        __syncthreads();
        #pragma unroll
        for (int i = 0; i < 8; ++i) {
            const int r = i * 16 + sr;
            float4 v = *(const float4*)(A + (size_t)(row0 + r) * 512 + kb + scol);
            if (MODE == 1) {
                const float4 u = *(const float4*)(A2 + (size_t)(row0 + r) * 512 + kb + scol);
                v.x -= u.x; v.y -= u.y; v.z -= u.z; v.w -= u.w;
            }
            bf16x4 hv, lv;
            hv[0] = (__bf16)v.x; hv[1] = (__bf16)v.y; hv[2] = (__bf16)v.z; hv[3] = (__bf16)v.w;
            lv[0] = (__bf16)(v.x - (float)hv[0]); lv[1] = (__bf16)(v.y - (float)hv[1]);
            lv[2] = (__bf16)(v.z - (float)hv[2]); lv[3] = (__bf16)(v.w - (float)hv[3]);
            *(bf16x4*)(Ah + r * 64 + lcol) = hv;
            *(bf16x4*)(Al + r * 64 + lcol) = lv;

            const float4 x = *(const float4*)(W + (size_t)(col0 + r) * 512 + kb + scol);
            bf16x4 hw, lw;
            hw[0] = (__bf16)x.x; hw[1] = (__bf16)x.y; hw[2] = (__bf16)x.z; hw[3] = (__bf16)x.w;
            lw[0] = (__bf16)(x.x - (float)hw[0]); lw[1] = (__bf16)(x.y - (float)hw[1]);
            lw[2] = (__bf16)(x.z - (float)hw[2]); lw[3] = (__bf16)(x.w - (float)hw[3]);
            *(bf16x4*)(Bh + r * 64 + lcol) = hw;
            *(bf16x4*)(Bl + r * 64 + lcol) = lw;
        }
        __syncthreads();
        #pragma unroll
        for (int s = 0; s < 2; ++s) {
            const int sx = s * 32;
            bf16x8 ah[2], al[2];
            #pragma unroll
            for (int mi = 0; mi < 2; ++mi) {
                ah[mi] = *(const bf16x8*)(Ah + (a_off[mi] ^ sx));
                al[mi] = *(const bf16x8*)(Al + (a_off[mi] ^ sx));
            }
            #pragma unroll
            for (int ni = 0; ni < 8; ++ni) {
                const bf16x8 bh = *(const bf16x8*)(Bh + (b_off[ni] ^ sx));
                const bf16x8 bl = *(const bf16x8*)(Bl + (b_off[ni] ^ sx));
                #pragma unroll
                for (int mi = 0; mi < 2; ++mi) {
                    acc[mi][ni] = __builtin_amdgcn_mfma_f32_16x16x32_bf16(ah[mi], bh, acc[mi][ni], 0, 0, 0);
                    acc[mi][ni] = __builtin_amdgcn_mfma_f32_16x16x32_bf16(ah[mi], bl, acc[mi][ni], 0, 0, 0);
                    acc[mi][ni] = __builtin_amdgcn_mfma_f32_16x16x32_bf16(al[mi], bh, acc[mi][ni], 0, 0, 0);
                }
            }
        }
    }

    #pragma unroll
    for (int mi = 0; mi < 2; ++mi) {
        #pragma unroll
        for (int reg = 0; reg < 4; ++reg) {
            const int row = row0 + w * 32 + mi * 16 + (lane >> 4) * 4 + reg;
            #pragma unroll
            for (int ni = 0; ni < 8; ++ni) {
                const int col = col0 + ni * 16 + (lane & 15);
                const float o = acc[mi][ni][reg] + bias[col];
                out0[(size_t)row * 512 + col] = o;
                if (MODE == 0) {
                    out1[(size_t)row * 512 + col] = o;
                    out2[(size_t)row * 512 + col] = (__bf16)o;
                }
            }
        }
    }
}

// ---------------------------------------------------------------------------
// Approx distance pass, 256x256 tile, BARRIER-MINIMAL double-buffer schedule:
//   d[t][c] ~= csq[c] - 2 * (r16[t] . cb16[c])
// R2 post-mortem: FETCH fix landed (542->74 MB) but MfmaUtil stuck at 31% ->
// the 16-barrier/8-lgkm-drain per iteration structure was the bottleneck at
// 2 waves/SIMD (1 block/CU, LDS=128KB). This version keeps the verified
// double-buffer + counted-vmcnt machinery but drops to 4 barriers/iteration,
// placed at the exact write-after-read retire points:
//   segA: stage B1lo/hi | read a0,b0(buf0,kk0) | lgkm0 | 32 MFMA
//   segB: read a1,b1(buf0,kk1) | lgkm0 | BAR_a | stage A2lo/hi | 32 MFMA
//         | vmcnt(4) | BAR_b
//   segC: stage B2lo/hi | read a0,b0(buf1,kk0) | lgkm0 | 32 MFMA
//   segD: read a1,b1(buf1,kk1) | lgkm0 | BAR_c | stage A3lo/hi | 32 MFMA
//         | vmcnt(4) | BAR_d
// lgkm0 BEFORE each barrier is load-bearing: all waves' reads of a region
// must COMPLETE before any wave issues the overwriting stage. vmcnt ledger:
// at BAR_b outstanding = prevA3(4)+B1(4)+A2(4); wait-to-4 completes exactly
// {prevA3, B1} = segC's inputs. At BAR_d completes {A2, B2} = next segA's.
// CHAIN=8 token tiles per block (grid 512 = 64 code-tiles x 8 token-groups)
// amortizes pipeline fill over 32 iterations. XCD column-stripe unchanged.
// Epilogue (per finished token tile): top-2 over wave's 64 cols, u32 keys,
// identical layout/tie-break as before.
// ---------------------------------------------------------------------------
constexpr int CHAIN = 8;                      // token tiles chained per block
constexpr size_t TILE_A = 256 * 512;          // elems per token tile

__global__ __launch_bounds__(512, 2)
void dist_approx8(const __bf16* __restrict__ Rh,   // [TT][512]
                  const __bf16* __restrict__ Ch,   // [KK][512]
                  const float* __restrict__ csq,
                  uint32_t* __restrict__ winners)
{
    __shared__ __bf16 As[2][256 * 64];   // 64 KB
    __shared__ __bf16 Bs[2][256 * 64];   // 64 KB

    const int tid  = threadIdx.x;
    const int lane = tid & 63;
    const int w    = tid >> 6;        // 0..7
    const int wm   = w >> 2;          // 0..1 : token half (128 rows)
    const int wn   = w & 3;           // 0..3 : code quarter (64 cols)

    // XCD column-stripe: xcd = b&7 owns code-cols [8*xcd, 8*xcd+8)
    const int b    = blockIdx.x;              // 0..511
    const int xcd  = b & 7;
    const int i    = b >> 3;                  // 0..63
    const int ct   = xcd * 8 + (i & 7);       // code tile 0..63
    const int tg   = i >> 3;                  // token group 0..7
    const int col0 = ct << 8;                 // code tile base
    const int rowb = tg << 11;                // 2048-token group base

    f32x4 acc[8][4] = {};   // [mi][ni]

    // staging coords: LDS stays linear for global_load_lds, swizzle applied
    // on the GLOBAL side (involution matches the read-side XOR).
    const int s_r = tid >> 3;                   // 0..63
    const int s_c = (tid & 7) ^ (s_r & 7);      // logical 16B chunk
    const __bf16* aS = Rh + (size_t)(rowb + s_r) * 512 + s_c * 8;
    const __bf16* bS = Ch + (size_t)(col0 + s_r) * 512 + s_c * 8;
    __bf16* const lA0 = &As[0][0]; __bf16* const lA1 = &As[1][0];
    __bf16* const lB0 = &Bs[0][0]; __bf16* const lB1 = &Bs[1][0];

    // A-source offset for K-tile q (q = 0..63): tile (q>>3), k-block (q&7)
#define AOFF(q) ((size_t)((q) >> 3) * TILE_A + (size_t)((q) & 7) * 64)

    // one half-tile (128 rows x 64 cols) = 2 rounds x (512 thr x 16 B)
#define STAGE(SRC, UOFF, DST)                                                      \
    {                                                                              \
        __builtin_amdgcn_global_load_lds((gas_ptr)((SRC) + (UOFF)),                \
                                         (las_ptr)((DST) + w * 8 * 64), 16, 0, 0); \
        __builtin_amdgcn_global_load_lds((gas_ptr)((SRC) + (UOFF) + 64 * 512),     \
                                         (las_ptr)((DST) + (64 + w * 8) * 64), 16, 0, 0); \
    }

    // fragment LDS offsets (elems), swizzle-compensated; kk=1 -> ^32 elems
    int aoff[8], boff[4];
    #pragma unroll
    for (int mi = 0; mi < 8; ++mi) {
        const int r = wm * 128 + mi * 16 + (lane & 15);
        aoff[mi] = r * 64 + (((lane >> 4) ^ (r & 7)) << 3);
    }
    #pragma unroll
    for (int ni = 0; ni < 4; ++ni) {
        const int r = wn * 64 + ni * 16 + (lane & 15);
        boff[ni] = r * 64 + (((lane >> 4) ^ (r & 7)) << 3);
    }

#define BAR __builtin_amdgcn_s_barrier()
// full lgkm drain + scheduling fence: guarantees this wave's ds_reads have
// COMPLETED (data in VGPRs) before anything below (barrier / MFMA) runs.
#define LGKM0 { asm volatile("s_waitcnt lgkmcnt(0)" ::: "memory"); \
                __builtin_amdgcn_sched_barrier(0); }
#define MFMA_QUAD(AF, A0, BV)                                                  \
    {                                                                          \
        __builtin_amdgcn_s_setprio(1);                                         \
        _Pragma("unroll")                                                      \
        for (int mi = 0; mi < 4; ++mi) {                                       \
            _Pragma("unroll")                                                  \
            for (int ni = 0; ni < 4; ++ni)                                     \
                acc[(A0) + mi][ni] = __builtin_amdgcn_mfma_f32_16x16x32_bf16(  \
                    (AF)[(A0) + mi], (BV)[ni], acc[(A0) + mi][ni], 0, 0, 0);   \
        }                                                                      \
        __builtin_amdgcn_s_setprio(0);                                         \
    }

    // ---- csq hoist (col0 is block-invariant); covered by prologue vmcnt(4)
    float csv[4];
    #pragma unroll
    for (int ni = 0; ni < 4; ++ni)
        csv[ni] = csq[col0 + wn * 64 + ni * 16 + (lane & 15)];
    const int gt = (col0 >> 6) + wn;   // winners 64-col granule index

    // ---- prologue: K-tile0 A+B -> buf0; K-tile1 A -> buf1.
    // vmcnt(4): buf0 complete, buf1-A (4 loads) in flight = steady state.
    STAGE(aS, AOFF(0),             lA0);
    STAGE(aS, AOFF(0) + 128 * 512, lA0 + 128 * 64);
    STAGE(bS, 0,                   lB0);
    STAGE(bS, 128 * 512,           lB0 + 128 * 64);
    STAGE(aS, AOFF(1),             lA1);
    STAGE(aS, AOFF(1) + 128 * 512, lA1 + 128 * 64);
    asm volatile("s_waitcnt vmcnt(4)" ::: "memory");
    BAR;

    bf16x8 a0[8], a1[8], b0[4], b1[4];

    for (int it = 0; it < 4 * CHAIN; ++it) {
        const bool more = it < 4 * CHAIN - 1;
        const size_t oB1 = (size_t)((2 * it + 1) & 7) * 64;   // B of K-tile 2it+1
        const size_t oA2 = AOFF(2 * it + 2);
        const size_t oB2 = (size_t)((2 * it + 2) & 7) * 64;
        const size_t oA3 = AOFF(2 * it + 3);

        // ---- segA: stage B1 (buf1-B, last read pre-BAR_d of prev iter);
        //      read buf0 kk0; 32 MFMA
        STAGE(bS, oB1,             lB1);
        STAGE(bS, 128 * 512 + oB1, lB1 + 128 * 64);
        #pragma unroll
        for (int mi = 0; mi < 8; ++mi) a0[mi] = *(const bf16x8*)(lA0 + aoff[mi]);
        #pragma unroll
        for (int ni = 0; ni < 4; ++ni) b0[ni] = *(const bf16x8*)(lB0 + boff[ni]);
        LGKM0;
        MFMA_QUAD(a0, 0, b0);
        MFMA_QUAD(a0, 4, b0);

        // ---- segB: read buf0 kk1; lgkm0 BEFORE BAR_a (all buf0 reads done
        //      chip-wide after the barrier); then stage A2 into buf0-A while
        //      the kk1 MFMAs run; counted drain; BAR_b licenses buf1 reads.
        #pragma unroll
        for (int mi = 0; mi < 8; ++mi) a1[mi] = *(const bf16x8*)(lA0 + (aoff[mi] ^ 32));
        #pragma unroll
        for (int ni = 0; ni < 4; ++ni) b1[ni] = *(const bf16x8*)(lB0 + (boff[ni] ^ 32));
        LGKM0;
        BAR;                                   // BAR_a
        if (more) {
            STAGE(aS, oA2,             lA0);
            STAGE(aS, oA2 + 128 * 512, lA0 + 128 * 64);
        }
        MFMA_QUAD(a1, 0, b1);
        MFMA_QUAD(a1, 4, b1);
        if (more) { asm volatile("s_waitcnt vmcnt(4)" ::: "memory"); }
        else      { asm volatile("s_waitcnt vmcnt(0)" ::: "memory"); }
        BAR;                                   // BAR_b: prevA3 + B1 landed

        // ---- segC: stage B2 (buf0-B, reads retired at BAR_a/BAR_b);
        //      read buf1 kk0; 32 MFMA
        if (more) {
            STAGE(bS, oB2,             lB0);
            STAGE(bS, 128 * 512 + oB2, lB0 + 128 * 64);
        }
        #pragma unroll
        for (int mi = 0; mi < 8; ++mi) a0[mi] = *(const bf16x8*)(lA1 + aoff[mi]);
        #pragma unroll
        for (int ni = 0; ni < 4; ++ni) b0[ni] = *(const bf16x8*)(lB1 + boff[ni]);
        LGKM0;
        MFMA_QUAD(a0, 0, b0);
        MFMA_QUAD(a0, 4, b0);

        // ---- segD: read buf1 kk1; lgkm0 + BAR_c retires buf1-A; stage A3;
        //      MFMA; counted drain {A2,B2}; BAR_d licenses next-iter buf0.
        #pragma unroll
        for (int mi = 0; mi < 8; ++mi) a1[mi] = *(const bf16x8*)(lA1 + (aoff[mi] ^ 32));
        #pragma unroll
        for (int ni = 0; ni < 4; ++ni) b1[ni] = *(const bf16x8*)(lB1 + (boff[ni] ^ 32));
        LGKM0;
        BAR;                                   // BAR_c
        if (more) {
            STAGE(aS, oA3,             lA1);
            STAGE(aS, oA3 + 128 * 512, lA1 + 128 * 64);
        }
        MFMA_QUAD(a1, 0, b1);
        MFMA_QUAD(a1, 4, b1);
        if (more) { asm volatile("s_waitcnt vmcnt(4)" ::: "memory"); }
        BAR;                                   // BAR_d

        // ---- per-tile epilogue: token tile done after every 4th iteration.
        // Top-2 over this wave's 64 cols, u32 keys; C/D layout (16x16x32):
        // col = lane&15, row = (lane>>4)*4 + reg.  Then re-zero acc.
        // Touches only regs/global/ds_permute -- no staged-LDS hazard.
        if ((it & 3) == 3) {
            const int r0t = rowb + (it >> 2) * 256;
            #pragma unroll
            for (int mi = 0; mi < 8; ++mi) {
                #pragma unroll
                for (int reg = 0; reg < 4; ++reg) {
                    uint32_t bk = 0xFFFFFFFFu, sk = 0xFFFFFFFFu;
                    #pragma unroll
                    for (int ni = 0; ni < 4; ++ni) {
                        const float d = fmaf(-2.0f, acc[mi][ni][reg], csv[ni]);
                        const uint32_t key = (sortable(d) & 0xFFFFFFC0u)
                                           | (uint32_t)(ni * 16 + (lane & 15));
                        const uint32_t nb = umin32(bk, key);
                        sk = umin32(sk, umax32(bk, key));
                        bk = nb;
                    }
                    #pragma unroll
                    for (int m = 1; m < 16; m <<= 1) {
                        const uint32_t ob = __shfl_xor((int)bk, m, 16);
                        const uint32_t os = __shfl_xor((int)sk, m, 16);
                        const uint32_t nb = umin32(bk, ob);
                        sk = umin32(umin32(sk, os), umax32(bk, ob));
                        bk = nb;
                    }
                    if ((lane & 15) == 0) {
                        const int row = r0t + wm * 128 + mi * 16 + (lane >> 4) * 4 + reg;
                        uint2 v; v.x = bk; v.y = sk;
                        *(uint2*)(winners + (size_t)row * 512 + gt * 2) = v;
                    }
                }
            }
            #pragma unroll
            for (int mi = 0; mi < 8; ++mi)
                #pragma unroll
                for (int ni = 0; ni < 4; ++ni)
                    acc[mi][ni] = (f32x4){0.f, 0.f, 0.f, 0.f};
        }
    }
#undef STAGE
#undef AOFF
#undef BAR
#undef LGKM0
#undef MFMA_QUAD
}

// ---------------------------------------------------------------------------
// Per token (one wave): approx top-8 of the 512 stored u32 keys, exact fp32
// rescore, pick true argmin (np tie-break), then fused residual update:
//   r[t] -= cb[best];  r16[t] = bf16(r[t])
// key -> global col: slot j holds tile j>>1 (64-col granule), col low 6 bits.
// ---------------------------------------------------------------------------
__global__ __launch_bounds__(256)
void select_rescore(const uint32_t* __restrict__ winners,
                    const float* __restrict__ CB, const float* __restrict__ csq,
                    float* __restrict__ R, __bf16* __restrict__ R16)
{
    const int w = threadIdx.x >> 6;
    const int lane = threadIdx.x & 63;
    const int token = blockIdx.x * 4 + w;

    const uint32_t* wt = winners + (size_t)token * 512;
    uint4 q0 = *(const uint4*)(wt + lane * 8);
    uint4 q1 = *(const uint4*)(wt + lane * 8 + 4);
    uint32_t k32[8] = {q0.x, q0.y, q0.z, q0.w, q1.x, q1.y, q1.z, q1.w};

    unsigned long long v[8];
    #pragma unroll
    for (int j = 0; j < 8; ++j) {
        const int gcol = ((lane * 8 + j) >> 1) * 64 + (int)(k32[j] & 63u);
        v[j] = ((unsigned long long)k32[j] << 32) | (uint32_t)gcol;
    }

    unsigned long long cand[TOPK];
    #pragma unroll
    for (int t = 0; t < TOPK; ++t) {
        unsigned long long mm = v[0];
        #pragma unroll
        for (int j = 1; j < 8; ++j) mm = umin64(mm, v[j]);
        #pragma unroll
        for (int m = 1; m < 64; m <<= 1)
            mm = umin64(mm, __shfl_xor(mm, m, 64));
        cand[t] = mm;
        #pragma unroll
        for (int j = 0; j < 8; ++j) if (v[j] == mm) v[j] = ~0ull;
    }

    // exact rescore in fp32
    float4 r0 = *(const float4*)(R + (size_t)token * 512 + lane * 8);
    float4 r1 = *(const float4*)(R + (size_t)token * 512 + lane * 8 + 4);

    unsigned long long best = ~0ull;
    #pragma unroll
    for (int t = 0; t < TOPK; ++t) {
        const int col = (int)(cand[t] & 0xFFFFFFFFull);
        const float4 c0 = *(const float4*)(CB + (size_t)col * 512 + lane * 8);
        const float4 c1 = *(const float4*)(CB + (size_t)col * 512 + lane * 8 + 4);
        float dot = r0.x * c0.x;
        dot = fmaf(r0.y, c0.y, dot); dot = fmaf(r0.z, c0.z, dot);
        dot = fmaf(r0.w, c0.w, dot); dot = fmaf(r1.x, c1.x, dot);
        dot = fmaf(r1.y, c1.y, dot); dot = fmaf(r1.z, c1.z, dot);
        dot = fmaf(r1.w, c1.w, dot);
        #pragma unroll
        for (int m = 1; m < 64; m <<= 1) dot += __shfl_xor(dot, m, 64);
        const float d = fmaf(-2.0f, dot, csq[col]);
        best = umin64(best, pack_di(d, col));
    }

    const int bcol = (int)(best & 0xFFFFFFFFull);
    const float4 c0 = *(const float4*)(CB + (size_t)bcol * 512 + lane * 8);
    const float4 c1 = *(const float4*)(CB + (size_t)bcol * 512 + lane * 8 + 4);
    r0.x -= c0.x; r0.y -= c0.y; r0.z -= c0.z; r0.w -= c0.w;
    r1.x -= c1.x; r1.y -= c1.y; r1.z -= c1.z; r1.w -= c1.w;
    *(float4*)(R + (size_t)token * 512 + lane * 8) = r0;
    *(float4*)(R + (size_t)token * 512 + lane * 8 + 4) = r1;
    bf16x8 h;
    h[0] = (__bf16)r0.x; h[1] = (__bf16)r0.y; h[2] = (__bf16)r0.z; h[3] = (__bf16)r0.w;
    h[4] = (__bf16)r1.x; h[5] = (__bf16)r1.y; h[6] = (__bf16)r1.z; h[7] = (__bf16)r1.w;
    *(bf16x8*)(R16 + (size_t)token * 512 + lane * 8) = h;
}

// ---------------------------------------------------------------------------
// Codebook prep (fused): c_sq[k] = ||cb[k]||^2 (fp32) and cb16 = bf16(cb)
// ---------------------------------------------------------------------------
__global__ __launch_bounds__(256)
void prep_cb(const float* __restrict__ CB, float* __restrict__ c_sq,
             __bf16* __restrict__ cb16)
{
    const int wave = threadIdx.x >> 6;
    const int lane = threadIdx.x & 63;
    const int row = blockIdx.x * 4 + wave;
    const float* p = CB + (size_t)row * DD + lane * 8;
    const float4 a = *(const float4*)p;
    const float4 b = *(const float4*)(p + 4);
    bf16x8 h;
    h[0] = (__bf16)a.x; h[1] = (__bf16)a.y; h[2] = (__bf16)a.z; h[3] = (__bf16)a.w;
    h[4] = (__bf16)b.x; h[5] = (__bf16)b.y; h[6] = (__bf16)b.z; h[7] = (__bf16)b.w;
    *(bf16x8*)(cb16 + (size_t)row * DD + lane * 8) = h;
    float s = a.x*a.x + a.y*a.y + a.z*a.z + a.w*a.w
            + b.x*b.x + b.y*b.y + b.z*b.z + b.w*b.w;
    #pragma unroll
    for (int m = 1; m < 64; m <<= 1) s += __shfl_xor(s, m, 64);
    if (lane == 0) c_sq[row] = s;
}

// ---------------------------------------------------------------------------
extern "C" void kernel_launch(void* const* d_in, const int* in_sizes, int n_in,
                              void* d_out, int out_size, void* d_ws, size_t ws_size,
                              hipStream_t stream)
{
    const float* x    = (const float*)d_in[0];
    const float* encw = (const float*)d_in[1];
    const float* encb = (const float*)d_in[2];
    const float* cb   = (const float*)d_in[3];
    const float* decw = (const float*)d_in[4];
    const float* decb = (const float*)d_in[5];
    float* out = (float*)d_out;

    // ws layout: z (32MB) | r (32MB) | cb16 (16MB) | r16 (16MB) | csq  (~96.1MB)
    float* z    = (float*)d_ws;                                  // TT*DD f32
    float* r    = z + (size_t)TT * DD;                           // TT*DD f32
    __bf16* cb16 = (__bf16*)(r + (size_t)TT * DD);               // KK*512 bf16
    __bf16* r16  = cb16 + (size_t)KK * DD;                       // TT*512 bf16
    float* csq  = (float*)(r16 + (size_t)TT * DD);               // KK f32
    // winners table lives in d_out (33.5 MB) — dead before decoder writes out
    uint32_t* winners = (uint32_t*)d_out;                        // TT*512 u32

    const dim3 blk(256);

    // encoder (MFMA hi/lo): z = x @ enc_w^T + enc_b ; r = z ; r16 = bf16(z)
    gemm_mfma<0><<<dim3(DD / 128, TT / 128), blk, 0, stream>>>(
        x, nullptr, encw, encb, z, r, r16);

    // codebook: exact squared norms + bf16 copy (fused, once per call)
    prep_cb<<<dim3(KK / 4), blk, 0, stream>>>(cb, csq, cb16);

    for (int s = 0; s < 2; ++s) {
        // 512 blocks = 64 code-tiles x 8 token-groups (CHAIN=8 tiles each)
        dist_approx8<<<dim3((KK / 256) * (TT / 256 / CHAIN)), dim3(512), 0, stream>>>(
            r16, cb16, csq, winners);
        select_rescore<<<dim3(TT / 4), blk, 0, stream>>>(winners, cb, csq, r, r16);
    }

    // decoder (MFMA hi/lo): out = (z - r) @ dec_w^T + dec_b
    gemm_mfma<1><<<dim3(DD / 128, TT / 128), blk, 0, stream>>>(
        z, r, decw, decb, out, nullptr, nullptr);
}